// Round 1
// baseline (28.340 us; speedup 1.0000x reference)
//
#include <hip/hip_runtime.h>
#include <math.h>

#define BATCH 2
#define LLEN  2080
#define MCH   2
#define TT    51
#define FF    80
#define HOP   40
#define KW    1600
#define NSUB  8
#define N2PER 5      // 40 / NSUB
#define OUTL  2040   // LLEN - OVERLAPS
#define PI_F  3.14159265358979323846f

// ---------------- Kernel 1: STFT (naive 80-point DFT) ----------------
// one block per (b,t,m), 80 threads; thread f computes X[f]
__global__ __launch_bounds__(FF) void stft_kernel(
    const float* __restrict__ xr, const float* __restrict__ xi,
    float2* __restrict__ X)
{
    __shared__ float2 xs[FF];
    __shared__ float2 tw[FF];
    int bid = blockIdx.x;
    int b   = bid / (TT * MCH);
    int rem = bid % (TT * MCH);
    int t   = rem / MCH;
    int mi  = rem % MCH;
    int j   = threadIdx.x;  // 0..79

    int gidx = (b * LLEN + t * HOP + j) * MCH + mi;
    xs[j] = make_float2(xr[gidx], xi[gidx]);
    float s, c;
    sincosf((2.0f * PI_F / FF) * (float)j, &s, &c);
    tw[j] = make_float2(c, s);   // e^{+i 2pi j/80}
    __syncthreads();

    int f = j;
    float2 acc = make_float2(0.f, 0.f);
    int r = 0;
    for (int jj = 0; jj < FF; ++jj) {
        float2 xv = xs[jj];
        float2 tv = tw[r];                 // need e^{-i..} = conj(tv)
        acc.x += xv.x * tv.x + xv.y * tv.y;
        acc.y += xv.y * tv.x - xv.x * tv.y;
        r += f; if (r >= FF) r -= FF;
    }
    X[((b * TT + t) * MCH + mi) * FF + f] = acc;
}

// ---------------- Kernel 2: delta = einsum(E, w) + bias ----------------
// one block per (b,t,m); 640 threads = 8 n2-subgroups x 80 freqs
__global__ __launch_bounds__(NSUB * FF) void delta_kernel(
    const float2* __restrict__ X,
    const float* __restrict__ wr, const float* __restrict__ wi,
    const float* __restrict__ br, const float* __restrict__ bi,
    float2* __restrict__ D)
{
    __shared__ float2 Yt[FF];
    __shared__ float2 Yp[FF];
    __shared__ float2 Wsh[KW];
    __shared__ float2 ZZ2[NSUB * 2 * FF];  // per-sub double-stored (160 each)

    int tid = threadIdx.x;       // 0..639
    int f   = tid % FF;
    int sub = tid / FF;
    int bid = blockIdx.x;
    int b   = bid / (TT * MCH);
    int rem = bid % (TT * MCH);
    int t   = rem / MCH;
    int mi  = rem % MCH;
    int tp  = (t + TT - 1) % TT;   // roll wraparound

    const float2* Yb  = X + ((b * TT + t ) * MCH + mi) * FF;
    const float2* Ypb = X + ((b * TT + tp) * MCH + mi) * FF;
    if (tid < FF)            Yt[tid]      = Yb[tid];
    else if (tid < 2 * FF)   Yp[tid - FF] = Ypb[tid - FF];
    for (int k = tid; k < KW; k += NSUB * FF)
        Wsh[k] = make_float2(wr[k], wi[k]);
    __syncthreads();

    float2* zz = &ZZ2[sub * 2 * FF];
    float2 acc = make_float2(0.f, 0.f);

    for (int i = 0; i < N2PER; ++i) {
        int jn = sub * N2PER + i;        // 0..39
        int n2 = jn - 20;
        // ZZ[g=f] = Yt[f]*conj(Yt[f-n2]) + Yp[f]*conj(Yp[f-n2])
        int gm = f - n2; if (gm >= FF) gm -= FF; if (gm < 0) gm += FF;
        float2 a  = Yt[f], bm = Yt[gm];
        float2 cc = Yp[f], dm = Yp[gm];
        float zr = a.x * bm.x + a.y * bm.y + cc.x * dm.x + cc.y * dm.y;
        float zi = a.y * bm.x - a.x * bm.y + cc.y * dm.x - cc.x * dm.y;
        // double-store: zz[j] = Z[(j-20) mod 80]; thread f writes j=f+20 and (f<60? f+100 : f-60)
        float2 z = make_float2(zr, zi);
        zz[f + 20] = z;
        zz[(f < 60) ? (f + 100) : (f - 60)] = z;
        __syncthreads();

        // S = sum_{n1} w[n1,n2] * Z[(f-n1) mod 80]; read zz[f + 40 - jn1]
        float sr = 0.f, si = 0.f;
        #pragma unroll
        for (int jn1 = 0; jn1 < 40; ++jn1) {
            float2 zv = zz[f + 40 - jn1];
            float2 wv = Wsh[jn1 * 40 + jn];
            sr += wv.x * zv.x - wv.y * zv.y;
            si += wv.x * zv.y + wv.y * zv.x;
        }
        // acc += Yt[(f-n2) mod 80] * S   (gm already = (f-n2) mod 80)
        float2 y = Yt[gm];
        acc.x += y.x * sr - y.y * si;
        acc.y += y.x * si + y.y * sr;
        __syncthreads();   // before zz overwrite next iter
    }

    // reduce partial deltas across the 8 subgroups (reuse ZZ2)
    ZZ2[sub * 2 * FF + f] = acc;
    __syncthreads();
    if (tid < FF) {
        float2 s = make_float2(br[0], bi[0]);
        for (int s2 = 0; s2 < NSUB; ++s2) {
            s.x += ZZ2[s2 * 2 * FF + tid].x;
            s.y += ZZ2[s2 * 2 * FF + tid].y;
        }
        D[((b * TT + t) * MCH + mi) * FF + tid] = s;
    }
}

// ---------------- Kernel 3: inverse DFT of delta ----------------
__global__ __launch_bounds__(FF) void idft_kernel(
    const float2* __restrict__ D, float2* __restrict__ Fr)
{
    __shared__ float2 ds[FF];
    __shared__ float2 tw[FF];
    int bid = blockIdx.x;
    int base = bid * FF;   // layout identical [b][t][m][f]
    int j = threadIdx.x;
    ds[j] = D[base + j];
    float s, c;
    sincosf((2.0f * PI_F / FF) * (float)j, &s, &c);
    tw[j] = make_float2(c, s);
    __syncthreads();

    float2 acc = make_float2(0.f, 0.f);
    int r = 0;
    for (int f = 0; f < FF; ++f) {
        float2 dv = ds[f];
        float2 tv = tw[r];   // e^{+i 2pi f j/80}
        acc.x += dv.x * tv.x - dv.y * tv.y;
        acc.y += dv.x * tv.y + dv.y * tv.x;
        r += j; if (r >= FF) r -= FF;
    }
    acc.x *= (1.0f / FF);
    acc.y *= (1.0f / FF);
    Fr[base + j] = acc;
}

// ---------------- Kernel 4: overlap-add, cov, residual, slice ----------------
__global__ void out_kernel(
    const float* __restrict__ xr, const float* __restrict__ xi,
    const float* __restrict__ ti, const float2* __restrict__ Fr,
    float* __restrict__ out, int out_size)
{
    int idx = blockIdx.x * blockDim.x + threadIdx.x;
    int tot = BATCH * OUTL * MCH;
    if (idx >= tot) return;
    int mi  = idx % MCH;
    int rem = idx / MCH;
    int lo  = rem % OUTL;
    int b   = rem / OUTL;
    int l   = lo + 20;    // OVERLAPS/2

    float P = powf(10.0f, ti[b * 4] * 0.1f) * 0.5f;   // /m with m=2

    int t1 = l / HOP;       // frame with j = l-40*t1 in [0,39]
    int t0 = t1 - 1;        // frame with j = l-40*t0 in [40,79]
    float2 acc = make_float2(0.f, 0.f);
    float cov = 0.f;
    if (t1 <= TT - 1) {
        float2 v = Fr[((b * TT + t1) * MCH + mi) * FF + (l - HOP * t1)];
        acc.x += v.x; acc.y += v.y; cov += 1.f;
    }
    if (t0 >= 0) {
        float2 v = Fr[((b * TT + t0) * MCH + mi) * FF + (l - HOP * t0)];
        acc.x += v.x; acc.y += v.y; cov += 1.f;
    }
    float inv = 1.0f / cov;
    acc.x *= inv; acc.y *= inv;

    int gi = (b * LLEN + l) * MCH + mi;
    float outr = xr[gi] + acc.x * P;
    if (out_size == tot) {
        out[idx] = outr;                       // real-only output
    } else {
        float outi = xi[gi] + acc.y * P;       // interleaved complex
        out[idx * 2]     = outr;
        out[idx * 2 + 1] = outi;
    }
}

extern "C" void kernel_launch(void* const* d_in, const int* in_sizes, int n_in,
                              void* d_out, int out_size, void* d_ws, size_t ws_size,
                              hipStream_t stream)
{
    const float* xr = (const float*)d_in[0];
    const float* xi = (const float*)d_in[1];
    const float* ti = (const float*)d_in[2];
    const float* wr = (const float*)d_in[3];
    const float* wi = (const float*)d_in[4];
    const float* br = (const float*)d_in[5];
    const float* bi = (const float*)d_in[6];

    const int nspec = BATCH * TT * MCH * FF;   // 16320 complex
    float2* X  = (float2*)d_ws;
    float2* D  = (float2*)((char*)d_ws + (size_t)nspec * sizeof(float2));
    float2* Fr = X;   // reuse X region for time-frames (X dead after delta_kernel)

    int nb = BATCH * TT * MCH;   // 204
    stft_kernel <<<nb, FF, 0, stream>>>(xr, xi, X);
    delta_kernel<<<nb, NSUB * FF, 0, stream>>>(X, wr, wi, br, bi, D);
    idft_kernel <<<nb, FF, 0, stream>>>(D, Fr);

    int tot = BATCH * OUTL * MCH;   // 8160
    out_kernel<<<(tot + 255) / 256, 256, 0, stream>>>(xr, xi, ti, Fr,
                                                      (float*)d_out, out_size);
}

// Round 2
// 21.698 us; speedup vs baseline: 1.3061x; 1.3061x over previous
//
#include <hip/hip_runtime.h>
#include <math.h>

#define BATCH 2
#define LLEN  2080
#define MCH   2
#define TT    51
#define FF    80
#define HOP   40
#define KW    1600
#define NSUB  8
#define N2PER 5      // 40 / NSUB
#define OUTL  2040
#define NT    (NSUB * FF)   // 640 threads
#define PI_F  3.14159265358979323846f

// ---------------- Kernel A: fused STFT + delta + iDFT ----------------
// one block per (b,t,m): 204 blocks x 640 threads
__global__ __launch_bounds__(NT) void fused_kernel(
    const float* __restrict__ xr, const float* __restrict__ xi,
    const float* __restrict__ wr, const float* __restrict__ wi,
    const float* __restrict__ br, const float* __restrict__ bi,
    float2* __restrict__ Fr)
{
    __shared__ float2 xs[2 * FF];        // samples: frame t [0:80), frame t-1 [80:160)
    __shared__ float2 tw[FF];            // e^{+i 2pi r/80}
    __shared__ float2 Yt[FF], Yp[FF];    // spectra
    __shared__ float2 Wsh[KW];           // w, layout [n1][n2]
    __shared__ float2 Zall[40][2 * FF];  // double-stored Z per n2: zz[j] = Z[(j-20)%80]
    __shared__ float2 red[NT];           // reduction scratch (reused 3x)
    __shared__ float2 dvec[FF];          // delta spectrum

    int tid = threadIdx.x;
    int f   = tid % FF;
    int sub = tid / FF;

    int bid = blockIdx.x;
    int b   = bid / (TT * MCH);
    int rem = bid % (TT * MCH);
    int t   = rem / MCH;
    int mi  = rem % MCH;
    int tp  = (t + TT - 1) % TT;   // roll wraparound

    // ---- Phase 0: load samples (160 thr), twiddles (80 thr), w (480 thr) ----
    if (tid < FF) {
        int g = (b * LLEN + t * HOP + tid) * MCH + mi;
        xs[tid] = make_float2(xr[g], xi[g]);
        float s, c;
        sincosf((2.0f * PI_F / FF) * (float)tid, &s, &c);
        tw[tid] = make_float2(c, s);
    } else if (tid < 2 * FF) {
        int j = tid - FF;
        int g = (b * LLEN + tp * HOP + j) * MCH + mi;
        xs[tid] = make_float2(xr[g], xi[g]);
    } else {
        for (int k = tid - 2 * FF; k < KW; k += NT - 2 * FF)
            Wsh[k] = make_float2(wr[k], wi[k]);
    }
    __syncthreads();

    // ---- Phase 1: STFT of both frames; 160 outputs x 4 partials x 20 MACs ----
    {
        int o    = tid >> 2;     // 0..159: output (frame, freq)
        int part = tid & 3;
        int ff   = o % FF;
        int frm  = o / FF;
        const float2* xb = &xs[frm * FF];
        float2 a = make_float2(0.f, 0.f);
        int j0 = part * 20;
        int r  = (ff * j0) % FF;
        for (int j = j0; j < j0 + 20; ++j) {
            float2 xv = xb[j];
            float2 tv = tw[r];            // conj applied below: e^{-i..}
            a.x += xv.x * tv.x + xv.y * tv.y;
            a.y += xv.y * tv.x - xv.x * tv.y;
            r += ff; if (r >= FF) r -= FF;
        }
        red[part * 160 + o] = a;
    }
    __syncthreads();
    if (tid < 2 * FF) {
        float2 s = make_float2(0.f, 0.f);
        for (int p = 0; p < 4; ++p) {
            float2 v = red[p * 160 + tid];
            s.x += v.x; s.y += v.y;
        }
        if (tid < FF) Yt[tid] = s; else Yp[tid - FF] = s;
    }
    __syncthreads();

    // ---- Phase 2: all Z rows upfront (3200 values, 5 per thread) ----
    for (int i = 0; i < 5; ++i) {
        int zi = tid + i * NT;          // 0..3199
        int jn = zi / FF;               // n2 index
        int g  = zi % FF;
        int n2 = jn - 20;
        int gm = g - n2; if (gm >= FF) gm -= FF; if (gm < 0) gm += FF;
        float2 a  = Yt[g],  bm = Yt[gm];
        float2 cc = Yp[g],  dm = Yp[gm];
        float zr = a.x * bm.x + a.y * bm.y + cc.x * dm.x + cc.y * dm.y;
        float zim = a.y * bm.x - a.x * bm.y + cc.y * dm.x - cc.x * dm.y;
        float2 z = make_float2(zr, zim);
        Zall[jn][g + 20] = z;
        Zall[jn][(g < 60) ? (g + 100) : (g - 60)] = z;
    }
    __syncthreads();

    // ---- Phase 3: MAC loop (sync-free): thread (f,sub), 5 n2 x 40 n1 ----
    {
        float2 acc = make_float2(0.f, 0.f);
        for (int i = 0; i < N2PER; ++i) {
            int jn = sub * N2PER + i;
            const float2* zz = Zall[jn];
            float sr = 0.f, si = 0.f;
            #pragma unroll
            for (int jn1 = 0; jn1 < 40; ++jn1) {
                float2 zv = zz[f + 40 - jn1];   // Z[(f-n1)%80]
                float2 wv = Wsh[jn1 * 40 + jn];
                sr += wv.x * zv.x - wv.y * zv.y;
                si += wv.x * zv.y + wv.y * zv.x;
            }
            int gm = f - (jn - 20); if (gm >= FF) gm -= FF; if (gm < 0) gm += FF;
            float2 y = Yt[gm];
            acc.x += y.x * sr - y.y * si;
            acc.y += y.x * si + y.y * sr;
        }
        red[tid] = acc;
    }
    __syncthreads();
    if (tid < FF) {
        float2 s = make_float2(br[0], bi[0]);
        for (int p = 0; p < NSUB; ++p) {
            float2 v = red[p * FF + tid];
            s.x += v.x; s.y += v.y;
        }
        dvec[tid] = s;
    }
    __syncthreads();

    // ---- Phase 4: iDFT; 80 outputs x 8 partials x 10 MACs ----
    {
        int j    = tid >> 3;    // time sample 0..79
        int part = tid & 7;
        float2 a = make_float2(0.f, 0.f);
        int f0 = part * 10;
        int r  = (j * f0) % FF;
        for (int ff2 = f0; ff2 < f0 + 10; ++ff2) {
            float2 dv = dvec[ff2];
            float2 tv = tw[r];             // e^{+i 2pi j f/80}
            a.x += dv.x * tv.x - dv.y * tv.y;
            a.y += dv.x * tv.y + dv.y * tv.x;
            r += j; if (r >= FF) r -= FF;
        }
        red[part * FF + j] = a;
    }
    __syncthreads();
    if (tid < FF) {
        float2 s = make_float2(0.f, 0.f);
        for (int p = 0; p < 8; ++p) {
            float2 v = red[p * FF + tid];
            s.x += v.x; s.y += v.y;
        }
        s.x *= (1.0f / FF);
        s.y *= (1.0f / FF);
        Fr[((b * TT + t) * MCH + mi) * FF + tid] = s;
    }
}

// ---------------- Kernel B: overlap-add, cov, residual, slice ----------------
__global__ void out_kernel(
    const float* __restrict__ xr, const float* __restrict__ xi,
    const float* __restrict__ ti, const float2* __restrict__ Fr,
    float* __restrict__ out, int out_size)
{
    int idx = blockIdx.x * blockDim.x + threadIdx.x;
    int tot = BATCH * OUTL * MCH;
    if (idx >= tot) return;
    int mi  = idx % MCH;
    int rem = idx / MCH;
    int lo  = rem % OUTL;
    int b   = rem / OUTL;
    int l   = lo + 20;    // OVERLAPS/2

    float P = powf(10.0f, ti[b * 4] * 0.1f) * 0.5f;   // /m with m=2

    int t1 = l / HOP;
    int t0 = t1 - 1;
    float2 acc = make_float2(0.f, 0.f);
    float cov = 0.f;
    if (t1 <= TT - 1) {
        float2 v = Fr[((b * TT + t1) * MCH + mi) * FF + (l - HOP * t1)];
        acc.x += v.x; acc.y += v.y; cov += 1.f;
    }
    if (t0 >= 0) {
        float2 v = Fr[((b * TT + t0) * MCH + mi) * FF + (l - HOP * t0)];
        acc.x += v.x; acc.y += v.y; cov += 1.f;
    }
    float inv = 1.0f / cov;
    acc.x *= inv; acc.y *= inv;

    int gi = (b * LLEN + l) * MCH + mi;
    float outr = xr[gi] + acc.x * P;
    if (out_size == tot) {
        out[idx] = outr;
    } else {
        float outi = xi[gi] + acc.y * P;
        out[idx * 2]     = outr;
        out[idx * 2 + 1] = outi;
    }
}

extern "C" void kernel_launch(void* const* d_in, const int* in_sizes, int n_in,
                              void* d_out, int out_size, void* d_ws, size_t ws_size,
                              hipStream_t stream)
{
    const float* xr = (const float*)d_in[0];
    const float* xi = (const float*)d_in[1];
    const float* ti = (const float*)d_in[2];
    const float* wr = (const float*)d_in[3];
    const float* wi = (const float*)d_in[4];
    const float* br = (const float*)d_in[5];
    const float* bi = (const float*)d_in[6];

    float2* Fr = (float2*)d_ws;   // 204*80 float2 = 130.6 KB

    int nb = BATCH * TT * MCH;    // 204
    fused_kernel<<<nb, NT, 0, stream>>>(xr, xi, wr, wi, br, bi, Fr);

    int tot = BATCH * OUTL * MCH; // 8160
    out_kernel<<<(tot + 255) / 256, 256, 0, stream>>>(xr, xi, ti, Fr,
                                                      (float*)d_out, out_size);
}

// Round 3
// 16.957 us; speedup vs baseline: 1.6712x; 1.2796x over previous
//
#include <hip/hip_runtime.h>
#include <math.h>

#define BATCH 2
#define LLEN  2080
#define MCH   2
#define TT    51
#define FF    80
#define HOP   40
#define KW    1600
#define OUTL  2040
#define NT    640
#define PI_F  3.14159265358979323846f

// ---------------- Kernel A: fused STFT + delta + iDFT ----------------
// one block per (b,t,m): 204 blocks x 640 threads
// phase-3 mapping: jn = tid>>4 (n2 index 0..39), fg = tid&15, f = fg*5 + q (q=0..4)
__global__ __launch_bounds__(NT) void fused_kernel(
    const float* __restrict__ xr, const float* __restrict__ xi,
    const float* __restrict__ wr, const float* __restrict__ wi,
    const float* __restrict__ br, const float* __restrict__ bi,
    float2* __restrict__ Fr)
{
    __shared__ float2 xs[2 * FF];      // samples: frame t [0:80), frame t-1 [80:160)
    __shared__ float2 tw[FF];          // e^{+i 2pi r/80}
    __shared__ float2 Yt2[2 * FF];     // double-stored Yt: Yt2[j] = Yt[(j-20)%80]
    __shared__ float2 Yp[FF];
    __shared__ float2 Wsh[KW];         // w, [n1][n2]
    __shared__ float2 Zall[40][2 * FF];// double-stored Z rows: Zall[jn][j] = Z[jn][(j-20)%80]
    __shared__ float2 dvec[FF];

    // overlays onto Zall (each used in a phase where Zall rows are dead / not yet built)
    float2* red  = &Zall[0][0];                       // 640 float2 (phase-1/4 scratch)
    float2 (*redD)[FF] = (float2(*)[FF])&Zall[0][0];  // 40x80 (post-phase-3 reduction)

    int tid = threadIdx.x;
    int bid = blockIdx.x;
    int b   = bid / (TT * MCH);
    int rem = bid % (TT * MCH);
    int t   = rem / MCH;
    int mi  = rem % MCH;
    int tp  = (t + TT - 1) % TT;

    // ---- Phase 0: load samples + twiddles + w ----
    if (tid < FF) {
        int g = (b * LLEN + t * HOP + tid) * MCH + mi;
        xs[tid] = make_float2(xr[g], xi[g]);
        float s, c;
        sincosf((2.0f * PI_F / FF) * (float)tid, &s, &c);
        tw[tid] = make_float2(c, s);
    } else if (tid < 2 * FF) {
        int j = tid - FF;
        int g = (b * LLEN + tp * HOP + j) * MCH + mi;
        xs[tid] = make_float2(xr[g], xi[g]);
    } else {
        for (int k = tid - 2 * FF; k < KW; k += NT - 2 * FF)
            Wsh[k] = make_float2(wr[k], wi[k]);
    }
    __syncthreads();

    // ---- Phase 1: STFT both frames; 160 outputs x 4 partials x 20 MACs ----
    {
        int o    = tid >> 2;
        int part = tid & 3;
        int ff   = o % FF;
        int frm  = o / FF;
        const float2* xb = &xs[frm * FF];
        float2 a = make_float2(0.f, 0.f);
        int j0 = part * 20;
        int r  = (ff * j0) % FF;
        for (int j = j0; j < j0 + 20; ++j) {
            float2 xv = xb[j];
            float2 tv = tw[r];             // conj applied: e^{-i..}
            a.x += xv.x * tv.x + xv.y * tv.y;
            a.y += xv.y * tv.x - xv.x * tv.y;
            r += ff; if (r >= FF) r -= FF;
        }
        red[part * 160 + o] = a;
    }
    __syncthreads();
    if (tid < 2 * FF) {
        float2 s = make_float2(0.f, 0.f);
        for (int p = 0; p < 4; ++p) {
            float2 v = red[p * 160 + tid];
            s.x += v.x; s.y += v.y;
        }
        if (tid < FF) {
            Yt2[tid + 20] = s;
            Yt2[(tid < 60) ? (tid + 100) : (tid - 60)] = s;
        } else {
            Yp[tid - FF] = s;
        }
    }
    __syncthreads();

    // ---- Phase 2: build all 40 Z rows (3200 values, 5/thread), double-stored ----
    for (int i = 0; i < 5; ++i) {
        int zi = tid + i * NT;
        int jn = zi / FF;
        int g  = zi % FF;
        int n2 = jn - 20;
        int gm = g - n2; if (gm >= FF) gm -= FF; if (gm < 0) gm += FF;
        float2 a  = Yt2[g + 20], bm = Yt2[gm + 20];
        float2 cc = Yp[g],       dm = Yp[gm];
        float zre = a.x * bm.x + a.y * bm.y + cc.x * dm.x + cc.y * dm.y;
        float zim = a.y * bm.x - a.x * bm.y + cc.y * dm.x - cc.x * dm.y;
        float2 z = make_float2(zre, zim);
        Zall[jn][g + 20] = z;
        Zall[jn][(g < 60) ? (g + 100) : (g - 60)] = z;
    }
    __syncthreads();

    // ---- Phase 3: register sliding-window MAC over n1 (1 LDS read per n1 step) ----
    float2 o0, o1, o2, o3, o4;
    int jn, fb;
    {
        jn = tid >> 4;          // n2 index
        int fg = tid & 15;
        fb = fg * 5;            // base frequency
        const float2* zz = Zall[jn];

        float2 S0 = make_float2(0.f,0.f), S1 = S0, S2 = S0, S3 = S0, S4 = S0;
        // win[q] = zz[fb + 40 - jn1 + q]
        float2 w0 = zz[fb + 40], w1 = zz[fb + 41], w2 = zz[fb + 42],
               w3 = zz[fb + 43], w4 = zz[fb + 44];
        #pragma unroll
        for (int jn1 = 0; jn1 < 40; ++jn1) {
            float2 wv = Wsh[jn1 * 40 + jn];
            S0.x += wv.x * w0.x - wv.y * w0.y;  S0.y += wv.x * w0.y + wv.y * w0.x;
            S1.x += wv.x * w1.x - wv.y * w1.y;  S1.y += wv.x * w1.y + wv.y * w1.x;
            S2.x += wv.x * w2.x - wv.y * w2.y;  S2.y += wv.x * w2.y + wv.y * w2.x;
            S3.x += wv.x * w3.x - wv.y * w3.y;  S3.y += wv.x * w3.y + wv.y * w3.x;
            S4.x += wv.x * w4.x - wv.y * w4.y;  S4.y += wv.x * w4.y + wv.y * w4.x;
            if (jn1 < 39) {
                float2 nv = zz[fb + 39 - jn1];
                w4 = w3; w3 = w2; w2 = w1; w1 = w0; w0 = nv;
            }
        }
        // multiply by Y[(f - n2) % 80] = Yt2[f - jn + 40]
        float2 y;
        y = Yt2[fb + 0 - jn + 40]; o0 = make_float2(y.x*S0.x - y.y*S0.y, y.x*S0.y + y.y*S0.x);
        y = Yt2[fb + 1 - jn + 40]; o1 = make_float2(y.x*S1.x - y.y*S1.y, y.x*S1.y + y.y*S1.x);
        y = Yt2[fb + 2 - jn + 40]; o2 = make_float2(y.x*S2.x - y.y*S2.y, y.x*S2.y + y.y*S2.x);
        y = Yt2[fb + 3 - jn + 40]; o3 = make_float2(y.x*S3.x - y.y*S3.y, y.x*S3.y + y.y*S3.x);
        y = Yt2[fb + 4 - jn + 40]; o4 = make_float2(y.x*S4.x - y.y*S4.y, y.x*S4.y + y.y*S4.x);
    }
    __syncthreads();           // all Zall reads done before overlay write
    redD[jn][fb + 0] = o0;
    redD[jn][fb + 1] = o1;
    redD[jn][fb + 2] = o2;
    redD[jn][fb + 3] = o3;
    redD[jn][fb + 4] = o4;
    __syncthreads();
    if (tid < FF) {
        float2 s = make_float2(br[0], bi[0]);
        for (int p = 0; p < 40; ++p) {
            float2 v = redD[p][tid];
            s.x += v.x; s.y += v.y;
        }
        dvec[tid] = s;
    }
    __syncthreads();

    // ---- Phase 4: iDFT; 80 outputs x 8 partials x 10 MACs ----
    {
        int j    = tid >> 3;
        int part = tid & 7;
        float2 a = make_float2(0.f, 0.f);
        int f0 = part * 10;
        int r  = (j * f0) % FF;
        for (int ff2 = f0; ff2 < f0 + 10; ++ff2) {
            float2 dv = dvec[ff2];
            float2 tv = tw[r];             // e^{+i 2pi j f/80}
            a.x += dv.x * tv.x - dv.y * tv.y;
            a.y += dv.x * tv.y + dv.y * tv.x;
            r += j; if (r >= FF) r -= FF;
        }
        red[part * FF + j] = a;
    }
    __syncthreads();
    if (tid < FF) {
        float2 s = make_float2(0.f, 0.f);
        for (int p = 0; p < 8; ++p) {
            float2 v = red[p * FF + tid];
            s.x += v.x; s.y += v.y;
        }
        s.x *= (1.0f / FF);
        s.y *= (1.0f / FF);
        Fr[((b * TT + t) * MCH + mi) * FF + tid] = s;
    }
}

// ---------------- Kernel B: overlap-add, cov, residual, slice ----------------
__global__ void out_kernel(
    const float* __restrict__ xr, const float* __restrict__ xi,
    const float* __restrict__ ti, const float2* __restrict__ Fr,
    float* __restrict__ out, int out_size)
{
    int idx = blockIdx.x * blockDim.x + threadIdx.x;
    int tot = BATCH * OUTL * MCH;
    if (idx >= tot) return;
    int mi  = idx % MCH;
    int rem = idx / MCH;
    int lo  = rem % OUTL;
    int b   = rem / OUTL;
    int l   = lo + 20;

    // 10^(x/10) = 2^(x * 0.1 * log2(10))
    float P = exp2f(ti[b * 4] * 0.33219280948873623f) * 0.5f;

    int t1 = l / HOP;
    int t0 = t1 - 1;
    float2 acc = make_float2(0.f, 0.f);
    float cov = 0.f;
    if (t1 <= TT - 1) {
        float2 v = Fr[((b * TT + t1) * MCH + mi) * FF + (l - HOP * t1)];
        acc.x += v.x; acc.y += v.y; cov += 1.f;
    }
    if (t0 >= 0) {
        float2 v = Fr[((b * TT + t0) * MCH + mi) * FF + (l - HOP * t0)];
        acc.x += v.x; acc.y += v.y; cov += 1.f;
    }
    float inv = 1.0f / cov;
    acc.x *= inv; acc.y *= inv;

    int gi = (b * LLEN + l) * MCH + mi;
    float outr = xr[gi] + acc.x * P;
    if (out_size == tot) {
        out[idx] = outr;
    } else {
        float outi = xi[gi] + acc.y * P;
        out[idx * 2]     = outr;
        out[idx * 2 + 1] = outi;
    }
}

extern "C" void kernel_launch(void* const* d_in, const int* in_sizes, int n_in,
                              void* d_out, int out_size, void* d_ws, size_t ws_size,
                              hipStream_t stream)
{
    const float* xr = (const float*)d_in[0];
    const float* xi = (const float*)d_in[1];
    const float* ti = (const float*)d_in[2];
    const float* wr = (const float*)d_in[3];
    const float* wi = (const float*)d_in[4];
    const float* br = (const float*)d_in[5];
    const float* bi = (const float*)d_in[6];

    float2* Fr = (float2*)d_ws;   // 204*80 float2 = 130.6 KB

    int nb = BATCH * TT * MCH;    // 204
    fused_kernel<<<nb, NT, 0, stream>>>(xr, xi, wr, wi, br, bi, Fr);

    int tot = BATCH * OUTL * MCH; // 8160
    out_kernel<<<(tot + 255) / 256, 256, 0, stream>>>(xr, xi, ti, Fr,
                                                      (float*)d_out, out_size);
}